// Round 1
// baseline (1535.154 us; speedup 1.0000x reference)
//
#include <hip/hip_runtime.h>
#include <math.h>

#define N_NODES  2000000
#define N_GRAPHS 8192
#define CDIM     128
#define G_PER    16        // graphs per block in final kernel
#define RED_BLOCKS 2048    // 8 blocks/CU on 256 CUs

// float atomic max via integer ordering trick.
// Requires destination initialized to -inf bit pattern.
__device__ __forceinline__ void atomicMaxF(float* addr, float v) {
    if (v >= 0.0f) {
        atomicMax((int*)addr, __float_as_int(v));
    } else {
        atomicMin((unsigned int*)addr, __float_as_uint(v));
    }
}

// ---------------- init: seg_sum = 0, seg_max = -inf ----------------
__global__ __launch_bounds__(256) void init_kernel(float4* __restrict__ seg_sum4,
                                                   float4* __restrict__ seg_max4) {
    int i = blockIdx.x * blockDim.x + threadIdx.x;   // one float4 per thread
    const int total4 = N_GRAPHS * CDIM / 4;
    if (i < total4) {
        float ninf = -__builtin_huge_valf();
        seg_sum4[i] = make_float4(0.f, 0.f, 0.f, 0.f);
        seg_max4[i] = make_float4(ninf, ninf, ninf, ninf);
    }
}

// ---------------- counts via binary search on sorted batch ----------------
__global__ __launch_bounds__(256) void count_kernel(const int* __restrict__ batch,
                                                    int* __restrict__ counts) {
    int g = blockIdx.x * blockDim.x + threadIdx.x;
    if (g >= N_GRAPHS) return;
    // lower_bound(g)
    int lo = 0, hi = N_NODES;
    while (lo < hi) { int mid = (lo + hi) >> 1; if (batch[mid] < g) lo = mid + 1; else hi = mid; }
    int start = lo;
    // lower_bound(g+1)
    hi = N_NODES;
    while (lo < hi) { int mid = (lo + hi) >> 1; if (batch[mid] < g + 1) lo = mid + 1; else hi = mid; }
    counts[g] = lo - start;
}

// ---------------- segment sum+max reduction (the HBM-bound kernel) -------------
// Block covers rows [start, end). Thread layout: q = tid&31 (float4 column quad),
// rl = tid>>5 (8 row lanes). Each thread keeps running sum/max for the current
// segment; flushes with atomics only on segment change (batch is sorted).
__global__ __launch_bounds__(256) void reduce_kernel(const float4* __restrict__ x4,
                                                     const int* __restrict__ batch,
                                                     float* __restrict__ seg_sum,
                                                     float* __restrict__ seg_max,
                                                     int rows_per_block) {
    const int start = blockIdx.x * rows_per_block;
    const int end   = min(start + rows_per_block, N_NODES);
    const int q  = threadIdx.x & 31;
    const int rl = threadIdx.x >> 5;

    const float ninf = -__builtin_huge_valf();
    float4 s = make_float4(0.f, 0.f, 0.f, 0.f);
    float4 m = make_float4(ninf, ninf, ninf, ninf);
    int cur = -1;

    for (int r = start + rl; r < end; r += 8) {
        int seg = batch[r];
        float4 v = x4[(size_t)r * (CDIM / 4) + q];
        if (seg != cur) {
            if (cur >= 0) {
                float* sp = seg_sum + (size_t)cur * CDIM + q * 4;
                float* mp = seg_max + (size_t)cur * CDIM + q * 4;
                atomicAdd(sp + 0, s.x); atomicAdd(sp + 1, s.y);
                atomicAdd(sp + 2, s.z); atomicAdd(sp + 3, s.w);
                atomicMaxF(mp + 0, m.x); atomicMaxF(mp + 1, m.y);
                atomicMaxF(mp + 2, m.z); atomicMaxF(mp + 3, m.w);
            }
            cur = seg;
            s = make_float4(0.f, 0.f, 0.f, 0.f);
            m = make_float4(ninf, ninf, ninf, ninf);
        }
        s.x += v.x; s.y += v.y; s.z += v.z; s.w += v.w;
        m.x = fmaxf(m.x, v.x); m.y = fmaxf(m.y, v.y);
        m.z = fmaxf(m.z, v.z); m.w = fmaxf(m.w, v.w);
    }
    if (cur >= 0) {
        float* sp = seg_sum + (size_t)cur * CDIM + q * 4;
        float* mp = seg_max + (size_t)cur * CDIM + q * 4;
        atomicAdd(sp + 0, s.x); atomicAdd(sp + 1, s.y);
        atomicAdd(sp + 2, s.z); atomicAdd(sp + 3, s.w);
        atomicMaxF(mp + 0, m.x); atomicMaxF(mp + 1, m.y);
        atomicMaxF(mp + 2, m.z); atomicMaxF(mp + 3, m.w);
    }
}

// ---------------- final: mean/max -> gated GEMM -> blend ----------------
// Block handles G_PER graphs. Stage mean/max in LDS (broadcast reads in GEMM).
// Thread t: output channels j0=2*(t&63), graph quarter gq=t>>6 (4 graphs each).
__global__ __launch_bounds__(256) void final_kernel(const float* __restrict__ seg_sum,
                                                    const float* __restrict__ seg_max,
                                                    const int* __restrict__ counts,
                                                    const float* __restrict__ W,
                                                    const float* __restrict__ bias,
                                                    float* __restrict__ out) {
    __shared__ float mean_s[G_PER][CDIM];
    __shared__ float maxx_s[G_PER][CDIM];

    const int g0  = blockIdx.x * G_PER;
    const int tid = threadIdx.x;

    // stage mean / max (empty segments -> 0 for both, matching reference)
    for (int idx = tid; idx < G_PER * CDIM; idx += 256) {
        int gl = idx >> 7;           // graph-local
        int ch = idx & (CDIM - 1);   // channel
        int g  = g0 + gl;
        int cnt = counts[g];
        float mv = 0.f, xv = 0.f;
        if (cnt > 0) {
            float inv = 1.0f / (float)cnt;
            mv = seg_sum[(size_t)g * CDIM + ch] * inv;
            xv = seg_max[(size_t)g * CDIM + ch];
        }
        mean_s[gl][ch] = mv;
        maxx_s[gl][ch] = xv;
    }
    __syncthreads();

    const int j0    = (tid & 63) * 2;  // two adjacent output channels
    const int gbase = (tid >> 6) * 4;  // four graphs

    float acc[4][2];
#pragma unroll
    for (int gl = 0; gl < 4; gl++) { acc[gl][0] = 0.f; acc[gl][1] = 0.f; }

    // K = 0..127 : mean part (W rows 0..127)
#pragma unroll 4
    for (int kq = 0; kq < CDIM / 4; kq++) {
        int k = kq * 4;
        float2 w0 = *(const float2*)(W + (size_t)(k + 0) * CDIM + j0);
        float2 w1 = *(const float2*)(W + (size_t)(k + 1) * CDIM + j0);
        float2 w2 = *(const float2*)(W + (size_t)(k + 2) * CDIM + j0);
        float2 w3 = *(const float2*)(W + (size_t)(k + 3) * CDIM + j0);
#pragma unroll
        for (int gl = 0; gl < 4; gl++) {
            float4 mv = *(const float4*)&mean_s[gbase + gl][k];
            acc[gl][0] += mv.x * w0.x + mv.y * w1.x + mv.z * w2.x + mv.w * w3.x;
            acc[gl][1] += mv.x * w0.y + mv.y * w1.y + mv.z * w2.y + mv.w * w3.y;
        }
    }
    // K = 128..255 : max part (W rows 128..255)
#pragma unroll 4
    for (int kq = 0; kq < CDIM / 4; kq++) {
        int k = kq * 4;
        const float* Wr = W + (size_t)(CDIM + k) * CDIM + j0;
        float2 w0 = *(const float2*)(Wr + 0 * CDIM);
        float2 w1 = *(const float2*)(Wr + 1 * CDIM);
        float2 w2 = *(const float2*)(Wr + 2 * CDIM);
        float2 w3 = *(const float2*)(Wr + 3 * CDIM);
#pragma unroll
        for (int gl = 0; gl < 4; gl++) {
            float4 xv = *(const float4*)&maxx_s[gbase + gl][k];
            acc[gl][0] += xv.x * w0.x + xv.y * w1.x + xv.z * w2.x + xv.w * w3.x;
            acc[gl][1] += xv.x * w0.y + xv.y * w1.y + xv.z * w2.y + xv.w * w3.y;
        }
    }

    float2 bb = *(const float2*)(bias + j0);
#pragma unroll
    for (int gl = 0; gl < 4; gl++) {
        int g = g0 + gbase + gl;
        float z0 = acc[gl][0] + bb.x;
        float z1 = acc[gl][1] + bb.y;
        float a0 = 1.0f / (1.0f + expf(-z0));
        float a1 = 1.0f / (1.0f + expf(-z1));
        float m0 = mean_s[gbase + gl][j0 + 0];
        float m1 = mean_s[gbase + gl][j0 + 1];
        float x0 = maxx_s[gbase + gl][j0 + 0];
        float x1 = maxx_s[gbase + gl][j0 + 1];
        float2 o;
        o.x = a0 * m0 + (1.0f - a0) * x0;
        o.y = a1 * m1 + (1.0f - a1) * x1;
        *(float2*)(out + (size_t)g * CDIM + j0) = o;
    }
}

extern "C" void kernel_launch(void* const* d_in, const int* in_sizes, int n_in,
                              void* d_out, int out_size, void* d_ws, size_t ws_size,
                              hipStream_t stream) {
    const float* x     = (const float*)d_in[0];
    const int*   batch = (const int*)d_in[1];
    const float* W     = (const float*)d_in[2];
    const float* bias  = (const float*)d_in[3];
    float*       out   = (float*)d_out;

    // workspace layout: seg_sum [G*C] f32 | seg_max [G*C] f32 | counts [G] i32
    float* seg_sum = (float*)d_ws;
    float* seg_max = seg_sum + (size_t)N_GRAPHS * CDIM;
    int*   counts  = (int*)(seg_max + (size_t)N_GRAPHS * CDIM);

    // 1) init accumulators (ws is re-poisoned before every timed launch)
    {
        int total4 = N_GRAPHS * CDIM / 4;
        int blocks = (total4 + 255) / 256;
        init_kernel<<<blocks, 256, 0, stream>>>((float4*)seg_sum, (float4*)seg_max);
    }
    // 2) per-graph counts (independent of 1)
    count_kernel<<<N_GRAPHS / 256, 256, 0, stream>>>(batch, counts);
    // 3) segment sum+max over x (HBM-bound)
    {
        int rpb = (N_NODES + RED_BLOCKS - 1) / RED_BLOCKS;   // 977
        reduce_kernel<<<RED_BLOCKS, 256, 0, stream>>>((const float4*)x, batch,
                                                      seg_sum, seg_max, rpb);
    }
    // 4) gated GEMM + blend
    final_kernel<<<N_GRAPHS / G_PER, 256, 0, stream>>>(seg_sum, seg_max, counts,
                                                       W, bias, out);
}